// Round 4
// baseline (249.419 us; speedup 1.0000x reference)
//
#include <hip/hip_runtime.h>

// PtConv: B=8, N=8192, C_IN=64, C_OUT=128, K=16, M=16, DIM=3
#define BATCH 8
#define NPTS  8192
#define CIN   64
#define COUT  128
#define KNN   16
#define MD    16
#define PTS   16            // points per block (conv kernel)
#define DT_STR 264          // fallback mono kernel only
#define AGG_STRIDE 1032     // s_agg per-point stride (shorts); 516 dw == 4 mod 32

#define NWT    (COUT * CIN * MD)          // 131072 bf16
#define NFBF   (BATCH * NPTS * CIN)       // 4194304 bf16
#define NPTS_G (BATCH * NPTS)             // 65536
#define NNBR   (NPTS_G * KNN)             // 1048576

typedef __attribute__((ext_vector_type(8))) short short8;
typedef __attribute__((ext_vector_type(4))) short short4v;
typedef __attribute__((ext_vector_type(4))) float f32x4;
typedef __attribute__((ext_vector_type(2))) float f32x2;

__device__ __forceinline__ short f2bf(float f) {
  unsigned u = __float_as_uint(f);
  u = (u + 0x7fffu + ((u >> 16) & 1u)) >> 16;   // RNE
  return (short)u;
}

// prep: Wt (bf16, transposed, k-permuted in mode 3); fbf (bf16 features,
// channel-interleaved when mode>=2: element c=ct*16+lr stored at lr*4+ct);
// Gc = collapsed layer-1; out tail = output_pts copy.
__global__ __launch_bounds__(256) void prep_kernel(
    const float* __restrict__ weight, const float* __restrict__ opts,
    const float* __restrict__ feats, const float* __restrict__ centers,
    const float* __restrict__ l1_w, const float* __restrict__ l1_b,
    short* __restrict__ Wt, short* __restrict__ fbf, float* __restrict__ Gc,
    float* __restrict__ out_tail, int mode) {
  int tid = blockIdx.x * 256 + threadIdx.x;
  if (mode >= 1 && tid < NWT) {
    int co = tid >> 10, o = tid & 1023;
    int k;
    if (mode == 3) {  // k(o): matches conv_kernel s_agg slot layout
      int m = o & 15, q = (o >> 4) & 3, r = (o >> 6) & 3, ct = o >> 8;
      k = ct * 256 + q * 64 + r * 16 + m;
    } else {
      k = o;
    }
    Wt[tid] = f2bf(weight[(size_t)k * COUT + co]);
  }
  if (mode >= 2 && tid < NFBF) {
    int row = tid >> 6, c = tid & 63;
    int lr = c & 15, ct = c >> 4;
    fbf[(size_t)row * CIN + lr * 4 + ct] = f2bf(feats[tid]);  // same cache line
  }
  if (mode == 3 && tid < 32) {
    float g0 = 0.f, g1 = 0.f, g2 = 0.f, cc = l1_b[tid];
    const float* wr = l1_w + tid * 48;
#pragma unroll
    for (int m = 0; m < 16; ++m) {
      g0 += wr[m]; g1 += wr[16 + m]; g2 += wr[32 + m];
    }
#pragma unroll
    for (int i = 0; i < 48; ++i) cc -= wr[i] * centers[i];
    Gc[tid * 3 + 0] = g0; Gc[tid * 3 + 1] = g1; Gc[tid * 3 + 2] = g2;
    Gc[96 + tid] = cc;
  }
  if (tid < BATCH * NPTS * 3) out_tail[tid] = opts[tid];
}

// kernel A: one thread per (point, neighbor). Collapsed layer-1 MLP.
// Output dws[ptg][m][k] (k contiguous) via LDS transpose + coalesced stores.
__global__ __launch_bounds__(256, 4) void mlp_kernel(
    const int* __restrict__ indices, const float* __restrict__ input_pts,
    const float* __restrict__ output_pts, const float* __restrict__ Gc,
    const float* __restrict__ l2_w, const float* __restrict__ l2_b,
    const float* __restrict__ l3_w, const float* __restrict__ l3_b,
    short* __restrict__ dws) {
  __shared__ __align__(16) short s_t[16 * 272];   // 8704 B, stride 272 -> conflict-free
  const int t = threadIdx.x;
  const int blk = blockIdx.x;                     // 4096 blocks
  const int nbr = blk * 256 + t;
  const int ptg = nbr >> 4, kk = nbr & 15;
  const int batch = ptg >> 13;
  const int id = indices[nbr];
  const float* op = output_pts + (size_t)ptg * 3;
  const float* ip = input_pts + ((size_t)(batch << 13) + id) * 3;
  const float px = ip[0] - op[0], py = ip[1] - op[1], pz = ip[2] - op[2];

  float h1[32];
#pragma unroll
  for (int o = 0; o < 32; ++o)
    h1[o] = fmaxf(Gc[o * 3] * px + Gc[o * 3 + 1] * py + Gc[o * 3 + 2] * pz + Gc[96 + o], 0.f);
  f32x2 h1v[16];
#pragma unroll
  for (int i = 0; i < 16; ++i) h1v[i] = (f32x2){h1[2 * i], h1[2 * i + 1]};
  float h2[16];
#pragma unroll
  for (int o = 0; o < 16; ++o) {
    const f32x2* wr = (const f32x2*)(l2_w + o * 32);
    f32x2 acc = {0.f, 0.f};
#pragma unroll
    for (int i = 0; i < 16; ++i) acc += h1v[i] * wr[i];
    h2[o] = fmaxf(acc[0] + acc[1] + l2_b[o], 0.f);
  }
  f32x2 h2v[8];
#pragma unroll
  for (int i = 0; i < 8; ++i) h2v[i] = (f32x2){h2[2 * i], h2[2 * i + 1]};
  const int pt_l = t >> 4;
#pragma unroll
  for (int o = 0; o < 16; ++o) {
    const f32x2* wr = (const f32x2*)(l3_w + o * 16);
    f32x2 acc = {0.f, 0.f};
#pragma unroll
    for (int i = 0; i < 8; ++i) acc += h2v[i] * wr[i];
    const float h3 = fmaxf(acc[0] + acc[1] + l3_b[o], 0.f) * 0.0625f;  // fold /K
    s_t[pt_l * 272 + o * 16 + kk] = f2bf(h3);
  }
  __syncthreads();
  // coalesced: thread t stores flat shorts [t*8, t*8+8) and [2048 + t*8, ...)
  const int pA = t >> 5, off = (t & 31) * 8;
  const short8 v0 = *(const short8*)&s_t[pA * 272 + off];
  const short8 v1 = *(const short8*)&s_t[(8 + pA) * 272 + off];
  short* gbase = dws + (size_t)blk * 4096;
  *(short8*)(gbase + t * 8) = v0;
  *(short8*)(gbase + 2048 + t * 8) = v1;
}

// kernel B: gather + agg-MFMA + output GEMM.
__global__ __launch_bounds__(256, 4) void conv_kernel(
    const int* __restrict__ indices, const short* __restrict__ fbf,
    const short* __restrict__ dws, const short* __restrict__ Wt,
    const float* __restrict__ bias, float* __restrict__ out) {
  __shared__ __align__(16) short s_agg[PTS * AGG_STRIDE];   // 33024 B -> 4 blocks/CU

  const int t = threadIdx.x, blk = blockIdx.x;              // 4096 blocks
  const int batch = blk >> 9, n0 = (blk & 511) * PTS;
  const int lane = t & 63, wv = t >> 6, quad = lane >> 4, lrow = lane & 15;
  const int ptg0 = batch * NPTS + n0 + wv * 4;              // this wave's 4 points

  // ---- issue ALL loads up front ----
  short4v bfr[4];
#pragma unroll
  for (int pp = 0; pp < 4; ++pp)
    bfr[pp] = *(const short4v*)(dws + ((size_t)(ptg0 + pp) << 8) + lrow * 16 + quad * 4);

  int4 idx4[4];
#pragma unroll
  for (int pp = 0; pp < 4; ++pp)   // 16 lanes broadcast-read the same 16B
    idx4[pp] = *(const int4*)(indices + ((size_t)(ptg0 + pp) << 4) + quad * 4);

  short4v g[4][4];
#pragma unroll
  for (int pp = 0; pp < 4; ++pp) {
    const int ids[4] = {idx4[pp].x, idx4[pp].y, idx4[pp].z, idx4[pp].w};
#pragma unroll
    for (int j = 0; j < 4; ++j)    // one b64 = this lane's 4 channels (interleaved fbf)
      g[pp][j] = *(const short4v*)(fbf + (((size_t)batch * NPTS + ids[j]) << 6) + lrow * 4);
  }

  // ---- phase 2: agg via MFMA 16x16x16 (contract K = 16 neighbors) ----
#pragma unroll
  for (int pp = 0; pp < 4; ++pp) {
    const int pt = wv * 4 + pp;
#pragma unroll
    for (int ct = 0; ct < 4; ++ct) {
      const short4v afr = {g[pp][0][ct], g[pp][1][ct], g[pp][2][ct], g[pp][3][ct]};
      const f32x4 dd = __builtin_amdgcn_mfma_f32_16x16x16bf16_1k(
          afr, bfr[pp], (f32x4){0.f, 0.f, 0.f, 0.f}, 0, 0, 0);
#pragma unroll
      for (int r = 0; r < 4; ++r)   // D: row(c_sub)=quad*4+r, col(m)=lrow
        s_agg[pt * AGG_STRIDE + (ct * 4 + r) * 64 + quad * 16 + lrow] = f2bf(dd[r]);
    }
  }
  __syncthreads();

  // ---- phase 3: MFMA GEMM [16 x 1024] @ [1024 x 128] ----
  f32x4 acc0 = {0.f, 0.f, 0.f, 0.f};
  f32x4 acc1 = {0.f, 0.f, 0.f, 0.f};
  const int co0 = wv * 32 + lrow, co1 = co0 + 16;
  const short* arow = s_agg + lrow * AGG_STRIDE + quad * 8;
  const short* wp0 = Wt + ((size_t)co0 << 10) + quad * 8;
  const short* wp1 = Wt + ((size_t)co1 << 10) + quad * 8;
#pragma unroll 8
  for (int kb = 0; kb < 32; ++kb) {
    const short8 a  = *(const short8*)(arow + kb * 32);
    const short8 b0 = *(const short8*)(wp0 + kb * 32);
    const short8 b1 = *(const short8*)(wp1 + kb * 32);
    acc0 = __builtin_amdgcn_mfma_f32_16x16x32_bf16(a, b0, acc0, 0, 0, 0);
    acc1 = __builtin_amdgcn_mfma_f32_16x16x32_bf16(a, b1, acc1, 0, 0, 0);
  }
  const float bi0 = bias[co0], bi1 = bias[co1];
#pragma unroll
  for (int r = 0; r < 4; ++r) {
    const int pt = quad * 4 + r;                 // D: row=quad*4+reg, col=lane&15
    const size_t rowo = ((size_t)(batch * NPTS + n0 + pt)) * COUT;
    out[rowo + co0] = acc0[r] + bi0;             // /K folded into d
    out[rowo + co1] = acc1[r] + bi1;
  }
}

// ---------------- fallback monolithic kernel, small workspace ----------------
template <int MODE>
__global__ __launch_bounds__(256, 3) void ptconv_mono(
    const float* __restrict__ features, const float* __restrict__ input_pts,
    const float* __restrict__ output_pts, const int* __restrict__ indices,
    const float* __restrict__ centers, const float* __restrict__ weight,
    const float* __restrict__ bias,
    const float* __restrict__ l1_w, const float* __restrict__ l1_b,
    const float* __restrict__ l2_w, const float* __restrict__ l2_b,
    const float* __restrict__ l3_w, const float* __restrict__ l3_b,
    const short* __restrict__ Wt, const short* __restrict__ fbf,
    float* __restrict__ out) {
  __shared__ __align__(16) short s_dT[MD * DT_STR];
  __shared__ __align__(16) short s_agg[PTS * AGG_STRIDE];
  __shared__ __align__(16) int   s_idx[PTS * KNN];

  const int t = threadIdx.x;
  const int blk = blockIdx.x;
  const int batch = blk >> 9;
  const int n0 = (blk & 511) * PTS;
  const int lane = t & 63;
  const int wv = t >> 6;
  const int quad = lane >> 4;
  const int lrow = lane & 15;

  s_idx[t] = indices[((size_t)batch * NPTS + n0) * KNN + t];
  {
    const int pt = t >> 4;
    const int id = s_idx[t];
    const float* op = &output_pts[((size_t)batch * NPTS + n0 + pt) * 3];
    const float* ip = &input_pts[((size_t)batch * NPTS + id) * 3];
    const float px = ip[0] - op[0], py = ip[1] - op[1], pz = ip[2] - op[2];
    f32x2 dv[24];
    {
      const f32x2 px2 = {px, px}, py2 = {py, py}, pz2 = {pz, pz};
      const f32x2* cx = (const f32x2*)centers;
      const f32x2* cy = (const f32x2*)(centers + 16);
      const f32x2* cz = (const f32x2*)(centers + 32);
#pragma unroll
      for (int i = 0; i < 8; ++i) {
        dv[i] = px2 - cx[i]; dv[8 + i] = py2 - cy[i]; dv[16 + i] = pz2 - cz[i];
      }
    }
    float h1[32];
#pragma unroll
    for (int o = 0; o < 32; ++o) {
      const f32x2* wr = (const f32x2*)(l1_w + o * 48);
      f32x2 acc = {0.f, 0.f};
#pragma unroll
      for (int i = 0; i < 24; ++i) acc += dv[i] * wr[i];
      h1[o] = fmaxf(acc[0] + acc[1] + l1_b[o], 0.f);
    }
    f32x2 h1v[16];
#pragma unroll
    for (int i = 0; i < 16; ++i) h1v[i] = (f32x2){h1[2 * i], h1[2 * i + 1]};
    float h2[16];
#pragma unroll
    for (int o = 0; o < 16; ++o) {
      const f32x2* wr = (const f32x2*)(l2_w + o * 32);
      f32x2 acc = {0.f, 0.f};
#pragma unroll
      for (int i = 0; i < 16; ++i) acc += h1v[i] * wr[i];
      h2[o] = fmaxf(acc[0] + acc[1] + l2_b[o], 0.f);
    }
    f32x2 h2v[8];
#pragma unroll
    for (int i = 0; i < 8; ++i) h2v[i] = (f32x2){h2[2 * i], h2[2 * i + 1]};
#pragma unroll
    for (int o = 0; o < 16; ++o) {
      const f32x2* wr = (const f32x2*)(l3_w + o * 16);
      f32x2 acc = {0.f, 0.f};
#pragma unroll
      for (int i = 0; i < 8; ++i) acc += h2v[i] * wr[i];
      s_dT[o * DT_STR + t] = f2bf(fmaxf(acc[0] + acc[1] + l3_b[o], 0.f));
    }
  }
  __syncthreads();
  {
#pragma unroll
    for (int pp = 0; pp < 4; ++pp) {
      const int pt = wv * 4 + pp;
      const short4v bfrag = *(const short4v*)&s_dT[lrow * DT_STR + pt * 16 + quad * 4];
      const int4 idx4 = *(const int4*)&s_idx[pt * 16 + quad * 4];
#pragma unroll
      for (int ct = 0; ct < 4; ++ct) {
        short4v afr;
#pragma unroll
        for (int j = 0; j < 4; ++j) {
          const int id = ((const int*)&idx4)[j];
          const size_t base = ((size_t)batch * NPTS + id) * CIN;
          if (MODE >= 2) afr[j] = fbf[base + lrow * 4 + ct];      // interleaved layout
          else           afr[j] = f2bf(features[base + ct * 16 + lrow]);
        }
        f32x4 dd = __builtin_amdgcn_mfma_f32_16x16x16bf16_1k(
            afr, bfrag, (f32x4){0.f, 0.f, 0.f, 0.f}, 0, 0, 0);
#pragma unroll
        for (int r = 0; r < 4; ++r) {
          const int rr = (r + quad) & 3;
          const int c = ct * 16 + quad * 4 + rr;
          s_agg[pt * AGG_STRIDE + c * 16 + lrow] = f2bf(dd[rr]);
        }
      }
    }
  }
  __syncthreads();
  {
    f32x4 acc0 = {0.f, 0.f, 0.f, 0.f};
    f32x4 acc1 = {0.f, 0.f, 0.f, 0.f};
    const int co0 = wv * 32 + lrow;
    const int co1 = co0 + 16;
    const short* arow = s_agg + lrow * AGG_STRIDE + quad * 8;
#pragma unroll 4
    for (int kb = 0; kb < 32; ++kb) {
      const short8 a = *(const short8*)(arow + kb * 32);
      short8 b0, b1;
      if (MODE >= 1) {
        b0 = *(const short8*)(Wt + (size_t)co0 * 1024 + kb * 32 + quad * 8);
        b1 = *(const short8*)(Wt + (size_t)co1 * 1024 + kb * 32 + quad * 8);
      } else {
#pragma unroll
        for (int j = 0; j < 8; ++j) {
          const int kk = kb * 32 + quad * 8 + j;
          b0[j] = f2bf(weight[(size_t)kk * COUT + co0]);
          b1[j] = f2bf(weight[(size_t)kk * COUT + co1]);
        }
      }
      acc0 = __builtin_amdgcn_mfma_f32_16x16x32_bf16(a, b0, acc0, 0, 0, 0);
      acc1 = __builtin_amdgcn_mfma_f32_16x16x32_bf16(a, b1, acc1, 0, 0, 0);
    }
    const float bi0 = bias[co0], bi1 = bias[co1];
#pragma unroll
    for (int r = 0; r < 4; ++r) {
      const int pt = quad * 4 + r;
      const size_t rowo = ((size_t)batch * NPTS + n0 + pt) * COUT;
      out[rowo + co0] = acc0[r] * 0.0625f + bi0;
      out[rowo + co1] = acc1[r] * 0.0625f + bi1;
    }
  }
}

extern "C" void kernel_launch(void* const* d_in, const int* in_sizes, int n_in,
                              void* d_out, int out_size, void* d_ws, size_t ws_size,
                              hipStream_t stream) {
  const float* features   = (const float*)d_in[0];
  const float* input_pts  = (const float*)d_in[1];
  const float* output_pts = (const float*)d_in[2];
  const int*   indices    = (const int*)d_in[3];
  const float* centers    = (const float*)d_in[4];
  const float* weight     = (const float*)d_in[5];
  const float* bias       = (const float*)d_in[6];
  const float* l1_w       = (const float*)d_in[7];
  const float* l1_b       = (const float*)d_in[8];
  const float* l2_w       = (const float*)d_in[9];
  const float* l2_b       = (const float*)d_in[10];
  const float* l3_w       = (const float*)d_in[11];
  const float* l3_b       = (const float*)d_in[12];
  float* out = (float*)d_out;

  short* Wt  = (short*)d_ws;
  short* fbf = (short*)d_ws + NWT;
  const size_t gc_off = (size_t)(NWT + NFBF) * 2;          // bytes
  float* Gc  = (float*)((char*)d_ws + gc_off);             // 128 floats
  short* dws = (short*)((char*)d_ws + gc_off + 512);
  const size_t need3 = gc_off + 512 + (size_t)NPTS_G * 256 * 2;   // ~42.2 MB

  int mode = 0;
  if (ws_size >= need3) mode = 3;
  else if (ws_size >= (size_t)(NWT + NFBF) * 2) mode = 2;
  else if (ws_size >= (size_t)NWT * 2) mode = 1;

  float* out_tail = out + (size_t)BATCH * NPTS * COUT;
  const int prep_elems = (mode >= 2) ? NFBF : BATCH * NPTS * 3;
  prep_kernel<<<(prep_elems + 255) / 256, 256, 0, stream>>>(
      weight, output_pts, features, centers, l1_w, l1_b, Wt, fbf, Gc, out_tail, mode);

  if (mode == 3) {
    mlp_kernel<<<NNBR / 256, 256, 0, stream>>>(
        indices, input_pts, output_pts, Gc, l2_w, l2_b, l3_w, l3_b, dws);
    conv_kernel<<<NPTS_G / PTS, 256, 0, stream>>>(indices, fbf, dws, Wt, bias, out);
  } else {
    const int grid = NPTS_G / PTS;
    if (mode == 2)
      ptconv_mono<2><<<grid, 256, 0, stream>>>(features, input_pts, output_pts, indices,
          centers, weight, bias, l1_w, l1_b, l2_w, l2_b, l3_w, l3_b, Wt, fbf, out);
    else if (mode == 1)
      ptconv_mono<1><<<grid, 256, 0, stream>>>(features, input_pts, output_pts, indices,
          centers, weight, bias, l1_w, l1_b, l2_w, l2_b, l3_w, l3_b, Wt, fbf, out);
    else
      ptconv_mono<0><<<grid, 256, 0, stream>>>(features, input_pts, output_pts, indices,
          centers, weight, bias, l1_w, l1_b, l2_w, l2_b, l3_w, l3_b, Wt, fbf, out);
  }
}

// Round 6
// 231.394 us; speedup vs baseline: 1.0779x; 1.0779x over previous
//
#include <hip/hip_runtime.h>

// PtConv: B=8, N=8192, C_IN=64, C_OUT=128, K=16, M=16, DIM=3
#define BATCH 8
#define NPTS  8192
#define CIN   64
#define COUT  128
#define KNN   16
#define MD    16
#define PTS   16            // points per block
#define DT_STR 264          // mono fallback only
#define SD_STR 272          // s_d per-point stride (shorts)
#define AGG_STRIDE 1032     // s_agg per-point stride (shorts); 516 dw == 4 mod 32

#define NWT    (COUT * CIN * MD)          // 131072 bf16
#define NFBF   (BATCH * NPTS * CIN)       // 4194304 bf16
#define NPTS_G (BATCH * NPTS)             // 65536

typedef __attribute__((ext_vector_type(8))) short short8;
typedef __attribute__((ext_vector_type(4))) short short4v;
typedef __attribute__((ext_vector_type(4))) float f32x4;
typedef __attribute__((ext_vector_type(2))) float f32x2;

__device__ __forceinline__ short f2bf(float f) {
  unsigned u = __float_as_uint(f);
  u = (u + 0x7fffu + ((u >> 16) & 1u)) >> 16;   // RNE
  return (short)u;
}

// prep (mode 3): Wt = bf16 W^T with k-slot permutation matching conv s_agg layout;
// fbf = channel-interleaved bf16 features; l2bf/l3bf = bf16 MLP weights;
// Gc4 = collapsed layer-1 [o][g0,g1,g2,c0]; out tail = output_pts copy.
__global__ __launch_bounds__(256) void prep_kernel(
    const float* __restrict__ weight, const float* __restrict__ opts,
    const float* __restrict__ feats, const float* __restrict__ centers,
    const float* __restrict__ l1_w, const float* __restrict__ l1_b,
    const float* __restrict__ l2_w, const float* __restrict__ l3_w,
    short* __restrict__ Wt, short* __restrict__ fbf,
    short* __restrict__ l2bf, short* __restrict__ l3bf, float* __restrict__ Gc4,
    float* __restrict__ out_tail, int mode) {
  int tid = blockIdx.x * 256 + threadIdx.x;
  if (mode >= 1 && tid < NWT) {
    int co = tid >> 10, o = tid & 1023;
    int k;
    if (mode == 3) {  // slot o = ct*256 + m*16 + q*4 + r  holds  k = ct*256 + q*64 + r*16 + m
      int r = o & 3, q = (o >> 2) & 3, m = (o >> 4) & 15, ct = o >> 8;
      k = ct * 256 + q * 64 + r * 16 + m;
    } else {
      k = o;
    }
    Wt[tid] = f2bf(weight[(size_t)k * COUT + co]);
  }
  if (mode >= 2 && tid < NFBF) {
    int row = tid >> 6, c = tid & 63;
    int lr = c & 15, ct = c >> 4;
    fbf[(size_t)row * CIN + lr * 4 + ct] = f2bf(feats[tid]);  // same cache line
  }
  if (mode == 3) {
    if (tid < 512) l2bf[tid] = f2bf(l2_w[tid]);   // [16 out][32 in]
    if (tid < 256) l3bf[tid] = f2bf(l3_w[tid]);   // [16 out][16 in]
    if (tid < 32) {
      float g0 = 0.f, g1 = 0.f, g2 = 0.f, cc = l1_b[tid];
      const float* wr = l1_w + tid * 48;
#pragma unroll
      for (int m = 0; m < 16; ++m) { g0 += wr[m]; g1 += wr[16 + m]; g2 += wr[32 + m]; }
#pragma unroll
      for (int i = 0; i < 48; ++i) cc -= wr[i] * centers[i];
      Gc4[tid * 4 + 0] = g0; Gc4[tid * 4 + 1] = g1; Gc4[tid * 4 + 2] = g2; Gc4[tid * 4 + 3] = cc;
    }
  }
  if (tid < BATCH * NPTS * 3) out_tail[tid] = opts[tid];
}

// Fused kernel: per-neighbor MLP (MFMA chain, biases in C operand) +
// neighbor aggregation (MFMA) + output GEMM (MFMA). One barrier total.
__global__ __launch_bounds__(256, 3) void conv_kernel(
    const int* __restrict__ indices, const short* __restrict__ fbf,
    const short* __restrict__ Wt, const short* __restrict__ l2bf,
    const short* __restrict__ l3bf, const float* __restrict__ Gc4,
    const float* __restrict__ l2_b, const float* __restrict__ l3_b,
    const float* __restrict__ input_pts, const float* __restrict__ output_pts,
    const float* __restrict__ bias, float* __restrict__ out) {
  __shared__ __align__(16) short s_d[PTS * SD_STR];         // 8704 B  [pt][m][nbr]
  __shared__ __align__(16) short s_agg[PTS * AGG_STRIDE];   // 33024 B [pt][slot]

  const int t = threadIdx.x, blk = blockIdx.x;              // 4096 blocks
  // XCD swizzle: all blocks of one batch land on one XCD (blk%8 heuristic) for fbf L2 locality
  const int w = ((blk & 7) << 9) | (blk >> 3);
  const int batch = w >> 9, n0 = (w & 511) * PTS;
  const int lane = t & 63, wv = t >> 6, quad = lane >> 4, lrow = lane & 15;
  const size_t bbase = (size_t)batch * NPTS;

  // thread t <-> (pt = wv*4+quad, nbr = lrow): own neighbor id + relative position
  const int myid = indices[(bbase + n0) * KNN + t];
  const float* op = output_pts + (bbase + n0 + wv * 4 + quad) * 3;
  const float* ip = input_pts + (bbase + myid) * 3;
  const float px = ip[0] - op[0], py = ip[1] - op[1], pz = ip[2] - op[2];

  // per-lane constants: collapsed-L1 rows for k = quad*8+j; W2/W3 A-frags;
  // layer-2/3 biases in MFMA C-layout (row = quad*4+r depends only on quad)
  f32x4 G[8];
#pragma unroll
  for (int j = 0; j < 8; ++j) G[j] = *(const f32x4*)(Gc4 + (quad * 8 + j) * 4);
  const short8  w2f = *(const short8*)(l2bf + lrow * 32 + quad * 8);
  const short4v w3f = *(const short4v*)(l3bf + lrow * 16 + quad * 4);
  const f32x4 b2f = *(const f32x4*)(l2_b + quad * 4);
  const f32x4 b3f = *(const f32x4*)(l3_b + quad * 4);

  // upfront feature gathers for all 4 points (ids via in-wave shuffle)
  short4v g[4][4];
#pragma unroll
  for (int pp = 0; pp < 4; ++pp)
#pragma unroll
    for (int j = 0; j < 4; ++j) {
      const int idn = __shfl(myid, pp * 16 + quad * 4 + j);
      g[pp][j] = *(const short4v*)(fbf + ((bbase + idn) << 6) + lrow * 4);
    }

#pragma unroll
  for (int pp = 0; pp < 4; ++pp) {
    const int pt = wv * 4 + pp;
    // ---- phase 0: MLP. h1 in B-frag layout [k=q*8+j][nbr=lrow] ----
    const float qx = __shfl(px, pp * 16 + lrow);
    const float qy = __shfl(py, pp * 16 + lrow);
    const float qz = __shfl(pz, pp * 16 + lrow);
    short8 h1f;
#pragma unroll
    for (int j = 0; j < 8; ++j) {
      const f32x4 Gx = G[j];
      h1f[j] = f2bf(fmaxf(Gx[0] * qx + Gx[1] * qy + Gx[2] * qz + Gx[3], 0.f));
    }
    // layer2: D[h2feat=q*4+r][nbr=lrow] = W2@h1 + b2  (bias via C operand)
    const f32x4 h2 = __builtin_amdgcn_mfma_f32_16x16x32_bf16(w2f, h1f, b2f, 0, 0, 0);
    short4v h2f;
#pragma unroll
    for (int r = 0; r < 4; ++r) h2f[r] = f2bf(fmaxf(h2[r], 0.f));
    // layer3: D[m=q*4+r][nbr=lrow] = W3@h2 + b3 = d^T
    const f32x4 h3 = __builtin_amdgcn_mfma_f32_16x16x16bf16_1k(w3f, h2f, b3f, 0, 0, 0);
#pragma unroll
    for (int r = 0; r < 4; ++r)     // s_d[pt][m][nbr]; /K folded here
      s_d[pt * SD_STR + (quad * 4 + r) * 16 + lrow] = f2bf(fmaxf(h3[r], 0.f) * 0.0625f);

    // ---- phase 2: agg via MFMA (wave-private s_d; in-order DS, no barrier) ----
    const short4v bfrag = *(const short4v*)&s_d[pt * SD_STR + lrow * 16 + quad * 4];
#pragma unroll
    for (int ct = 0; ct < 4; ++ct) {
      const short4v afr = {g[pp][0][ct], g[pp][1][ct], g[pp][2][ct], g[pp][3][ct]};
      const f32x4 dd = __builtin_amdgcn_mfma_f32_16x16x16bf16_1k(
          afr, bfrag, (f32x4){0.f, 0.f, 0.f, 0.f}, 0, 0, 0);
      short4v sv;
#pragma unroll
      for (int r = 0; r < 4; ++r) sv[r] = f2bf(dd[r]);
      // slot = ct*256 + m*16 + q*4 + r  (contiguous b64; 4 dw/bank uniform -> conflict-free)
      *(short4v*)&s_agg[pt * AGG_STRIDE + ct * 256 + lrow * 16 + quad * 4] = sv;
    }
  }
  __syncthreads();

  // ---- phase 3: MFMA GEMM [16 x 1024] @ [1024 x 128] ----
  f32x4 acc0 = {0.f, 0.f, 0.f, 0.f};
  f32x4 acc1 = {0.f, 0.f, 0.f, 0.f};
  const int co0 = wv * 32 + lrow, co1 = co0 + 16;
  const short* arow = s_agg + lrow * AGG_STRIDE + quad * 8;
  const short* wp0 = Wt + ((size_t)co0 << 10) + quad * 8;
  const short* wp1 = Wt + ((size_t)co1 << 10) + quad * 8;
#pragma unroll 8
  for (int kb = 0; kb < 32; ++kb) {
    const short8 a  = *(const short8*)(arow + kb * 32);
    const short8 b0 = *(const short8*)(wp0 + kb * 32);
    const short8 b1 = *(const short8*)(wp1 + kb * 32);
    acc0 = __builtin_amdgcn_mfma_f32_16x16x32_bf16(a, b0, acc0, 0, 0, 0);
    acc1 = __builtin_amdgcn_mfma_f32_16x16x32_bf16(a, b1, acc1, 0, 0, 0);
  }
  const float bi0 = bias[co0], bi1 = bias[co1];
#pragma unroll
  for (int r = 0; r < 4; ++r) {
    const int pt = quad * 4 + r;                 // D: row=quad*4+reg, col=lane&15
    const size_t rowo = (bbase + n0 + pt) * COUT;
    out[rowo + co0] = acc0[r] + bi0;
    out[rowo + co1] = acc1[r] + bi1;
  }
}

// ---------------- fallback monolithic kernel, small workspace ----------------
template <int MODE>
__global__ __launch_bounds__(256, 3) void ptconv_mono(
    const float* __restrict__ features, const float* __restrict__ input_pts,
    const float* __restrict__ output_pts, const int* __restrict__ indices,
    const float* __restrict__ centers, const float* __restrict__ weight,
    const float* __restrict__ bias,
    const float* __restrict__ l1_w, const float* __restrict__ l1_b,
    const float* __restrict__ l2_w, const float* __restrict__ l2_b,
    const float* __restrict__ l3_w, const float* __restrict__ l3_b,
    const short* __restrict__ Wt, const short* __restrict__ fbf,
    float* __restrict__ out) {
  __shared__ __align__(16) short s_dT[MD * DT_STR];
  __shared__ __align__(16) short s_agg[PTS * AGG_STRIDE];
  __shared__ __align__(16) int   s_idx[PTS * KNN];

  const int t = threadIdx.x;
  const int blk = blockIdx.x;
  const int batch = blk >> 9;
  const int n0 = (blk & 511) * PTS;
  const int lane = t & 63;
  const int wv = t >> 6;
  const int quad = lane >> 4;
  const int lrow = lane & 15;

  s_idx[t] = indices[((size_t)batch * NPTS + n0) * KNN + t];
  {
    const int pt = t >> 4;
    const int id = s_idx[t];
    const float* op = &output_pts[((size_t)batch * NPTS + n0 + pt) * 3];
    const float* ip = &input_pts[((size_t)batch * NPTS + id) * 3];
    const float px = ip[0] - op[0], py = ip[1] - op[1], pz = ip[2] - op[2];
    f32x2 dv[24];
    {
      const f32x2 px2 = {px, px}, py2 = {py, py}, pz2 = {pz, pz};
      const f32x2* cx = (const f32x2*)centers;
      const f32x2* cy = (const f32x2*)(centers + 16);
      const f32x2* cz = (const f32x2*)(centers + 32);
#pragma unroll
      for (int i = 0; i < 8; ++i) {
        dv[i] = px2 - cx[i]; dv[8 + i] = py2 - cy[i]; dv[16 + i] = pz2 - cz[i];
      }
    }
    float h1[32];
#pragma unroll
    for (int o = 0; o < 32; ++o) {
      const f32x2* wr = (const f32x2*)(l1_w + o * 48);
      f32x2 acc = {0.f, 0.f};
#pragma unroll
      for (int i = 0; i < 24; ++i) acc += dv[i] * wr[i];
      h1[o] = fmaxf(acc[0] + acc[1] + l1_b[o], 0.f);
    }
    f32x2 h1v[16];
#pragma unroll
    for (int i = 0; i < 16; ++i) h1v[i] = (f32x2){h1[2 * i], h1[2 * i + 1]};
    float h2[16];
#pragma unroll
    for (int o = 0; o < 16; ++o) {
      const f32x2* wr = (const f32x2*)(l2_w + o * 32);
      f32x2 acc = {0.f, 0.f};
#pragma unroll
      for (int i = 0; i < 16; ++i) acc += h1v[i] * wr[i];
      h2[o] = fmaxf(acc[0] + acc[1] + l2_b[o], 0.f);
    }
    f32x2 h2v[8];
#pragma unroll
    for (int i = 0; i < 8; ++i) h2v[i] = (f32x2){h2[2 * i], h2[2 * i + 1]};
#pragma unroll
    for (int o = 0; o < 16; ++o) {
      const f32x2* wr = (const f32x2*)(l3_w + o * 16);
      f32x2 acc = {0.f, 0.f};
#pragma unroll
      for (int i = 0; i < 8; ++i) acc += h2v[i] * wr[i];
      s_dT[o * DT_STR + t] = f2bf(fmaxf(acc[0] + acc[1] + l3_b[o], 0.f));
    }
  }
  __syncthreads();
  {
#pragma unroll
    for (int pp = 0; pp < 4; ++pp) {
      const int pt = wv * 4 + pp;
      const short4v bfrag = *(const short4v*)&s_dT[lrow * DT_STR + pt * 16 + quad * 4];
      const int4 idx4 = *(const int4*)&s_idx[pt * 16 + quad * 4];
#pragma unroll
      for (int ct = 0; ct < 4; ++ct) {
        short4v afr;
#pragma unroll
        for (int j = 0; j < 4; ++j) {
          const int id = ((const int*)&idx4)[j];
          const size_t base = ((size_t)batch * NPTS + id) * CIN;
          if (MODE >= 2) afr[j] = fbf[base + lrow * 4 + ct];      // interleaved layout
          else           afr[j] = f2bf(features[base + ct * 16 + lrow]);
        }
        f32x4 dd = __builtin_amdgcn_mfma_f32_16x16x16bf16_1k(
            afr, bfrag, (f32x4){0.f, 0.f, 0.f, 0.f}, 0, 0, 0);
#pragma unroll
        for (int r = 0; r < 4; ++r) {
          const int rr = (r + quad) & 3;
          const int c = ct * 16 + quad * 4 + rr;
          s_agg[pt * AGG_STRIDE + c * 16 + lrow] = f2bf(dd[rr]);
        }
      }
    }
  }
  __syncthreads();
  {
    f32x4 acc0 = {0.f, 0.f, 0.f, 0.f};
    f32x4 acc1 = {0.f, 0.f, 0.f, 0.f};
    const int co0 = wv * 32 + lrow;
    const int co1 = co0 + 16;
    const short* arow = s_agg + lrow * AGG_STRIDE + quad * 8;
#pragma unroll 4
    for (int kb = 0; kb < 32; ++kb) {
      const short8 a = *(const short8*)(arow + kb * 32);
      short8 b0, b1;
      if (MODE >= 1) {
        b0 = *(const short8*)(Wt + (size_t)co0 * 1024 + kb * 32 + quad * 8);
        b1 = *(const short8*)(Wt + (size_t)co1 * 1024 + kb * 32 + quad * 8);
      } else {
#pragma unroll
        for (int j = 0; j < 8; ++j) {
          const int kk = kb * 32 + quad * 8 + j;
          b0[j] = f2bf(weight[(size_t)kk * COUT + co0]);
          b1[j] = f2bf(weight[(size_t)kk * COUT + co1]);
        }
      }
      acc0 = __builtin_amdgcn_mfma_f32_16x16x32_bf16(a, b0, acc0, 0, 0, 0);
      acc1 = __builtin_amdgcn_mfma_f32_16x16x32_bf16(a, b1, acc1, 0, 0, 0);
    }
    const float bi0 = bias[co0], bi1 = bias[co1];
#pragma unroll
    for (int r = 0; r < 4; ++r) {
      const int pt = quad * 4 + r;
      const size_t rowo = ((size_t)batch * NPTS + n0 + pt) * COUT;
      out[rowo + co0] = acc0[r] * 0.0625f + bi0;
      out[rowo + co1] = acc1[r] * 0.0625f + bi1;
    }
  }
}

extern "C" void kernel_launch(void* const* d_in, const int* in_sizes, int n_in,
                              void* d_out, int out_size, void* d_ws, size_t ws_size,
                              hipStream_t stream) {
  const float* features   = (const float*)d_in[0];
  const float* input_pts  = (const float*)d_in[1];
  const float* output_pts = (const float*)d_in[2];
  const int*   indices    = (const int*)d_in[3];
  const float* centers    = (const float*)d_in[4];
  const float* weight     = (const float*)d_in[5];
  const float* bias       = (const float*)d_in[6];
  const float* l1_w       = (const float*)d_in[7];
  const float* l1_b       = (const float*)d_in[8];
  const float* l2_w       = (const float*)d_in[9];
  const float* l2_b       = (const float*)d_in[10];
  const float* l3_w       = (const float*)d_in[11];
  const float* l3_b       = (const float*)d_in[12];
  float* out = (float*)d_out;

  short* Wt   = (short*)d_ws;
  short* fbf  = Wt + NWT;
  short* l2bf = fbf + NFBF;
  short* l3bf = l2bf + 512;
  float* Gc4  = (float*)(l3bf + 256);       // 128 floats (NWT+NFBF+768 shorts = even -> 4B aligned; base 16B aligned)
  const size_t need3 = (size_t)(NWT + NFBF + 512 + 256) * 2 + 512;

  int mode = 0;
  if (ws_size >= need3) mode = 3;
  else if (ws_size >= (size_t)(NWT + NFBF) * 2) mode = 2;
  else if (ws_size >= (size_t)NWT * 2) mode = 1;

  float* out_tail = out + (size_t)BATCH * NPTS * COUT;
  const int prep_elems = (mode >= 2) ? NFBF : BATCH * NPTS * 3;
  prep_kernel<<<(prep_elems + 255) / 256, 256, 0, stream>>>(
      weight, output_pts, features, centers, l1_w, l1_b, l2_w, l3_w,
      Wt, fbf, l2bf, l3bf, Gc4, out_tail, mode);

  const int grid = NPTS_G / PTS;   // 4096
  if (mode == 3) {
    conv_kernel<<<grid, 256, 0, stream>>>(
        indices, fbf, Wt, l2bf, l3bf, Gc4, l2_b, l3_b, input_pts, output_pts, bias, out);
  } else if (mode == 2) {
    ptconv_mono<2><<<grid, 256, 0, stream>>>(features, input_pts, output_pts, indices,
        centers, weight, bias, l1_w, l1_b, l2_w, l2_b, l3_w, l3_b, Wt, fbf, out);
  } else if (mode == 1) {
    ptconv_mono<1><<<grid, 256, 0, stream>>>(features, input_pts, output_pts, indices,
        centers, weight, bias, l1_w, l1_b, l2_w, l2_b, l3_w, l3_b, Wt, fbf, out);
  } else {
    ptconv_mono<0><<<grid, 256, 0, stream>>>(features, input_pts, output_pts, indices,
        centers, weight, bias, l1_w, l1_b, l2_w, l2_b, l3_w, l3_b, Wt, fbf, out);
  }
}